// Round 3
// baseline (320.347 us; speedup 1.0000x reference)
//
#include <hip/hip_runtime.h>
#include <hip/hip_bf16.h>

// Causal MHA forward, B=4 T=2048 C=1024 H=16 D=64. fp32 in/out, bf16 MFMA inside.
// Round 7: VALU diet. Round-6 structure kept (in-register P via swapped QK^T +
// permlane, 64-key XOR-swizzled double-buffered stages, XCD clustering), plus:
//  - all fp32->bf16 conversion via single-instruction v_cvt_pk_bf16_f32
//    (inline asm; no builtin on gfx950). HIP __float2bfloat16 is ~8 VALU ops;
//    rocprof showed ~920 VALU-cyc/wave-stage, f2b was the dominant share.
//  - lsum split into 4 independent partials (no 16-deep serial FP add chain)
//  - s_setprio(1) around MFMA clusters (T5)
//  - DMA pointers strength-reduced by explicit increments

#define Bsz 4
#define Tsz 2048
#define Csz 1024
#define Hn  16
#define Dh  64

typedef unsigned short u16;
typedef __attribute__((ext_vector_type(8))) short bf16x8;   // 8 bf16 = 4 VGPRs
typedef __attribute__((ext_vector_type(4))) float f32x4;
typedef __attribute__((ext_vector_type(4))) unsigned int u32x4;
typedef __attribute__((ext_vector_type(2))) unsigned int u32x2;

// packed fp32x2 -> bf16x2 (RNE), single VALU instruction. lo in bits 15:0.
__device__ __forceinline__ unsigned pk2(float lo, float hi) {
  unsigned r;
  asm("v_cvt_pk_bf16_f32 %0, %1, %2" : "=v"(r) : "v"(lo), "v"(hi));
  return r;
}

__device__ __forceinline__ u16 f2b(float f) {
  unsigned r;
  asm("v_cvt_pk_bf16_f32 %0, %1, %1" : "=v"(r) : "v"(f));
  return (u16)r;
}

// async global->LDS, 16B per lane; lds base must be wave-uniform (lane*16 implicit)
__device__ __forceinline__ void gld_lds16(const void* g, void* lds) {
  __builtin_amdgcn_global_load_lds(
      (const __attribute__((address_space(1))) unsigned int*)g,
      (__attribute__((address_space(3))) unsigned int*)lds, 16, 0, 0);
}

// ---------------- fp32 -> bf16 elementwise (8 elems/thread) ----------------
__global__ __launch_bounds__(256) void cvt_f32_bf16(const float* __restrict__ in,
                                                    u16* __restrict__ out) {
  size_t i = ((size_t)blockIdx.x * 256 + threadIdx.x) * 8;
  f32x4 a = *(const f32x4*)(in + i);
  f32x4 b = *(const f32x4*)(in + i + 4);
  u32x4 r;
  r.x = pk2(a[0], a[1]); r.y = pk2(a[2], a[3]);
  r.z = pk2(b[0], b[1]); r.w = pk2(b[2], b[3]);
  *(u32x4*)(out + i) = r;
}

// ---------------- fp32 (R,C) -> bf16 transposed (C,R) ----------------
__global__ __launch_bounds__(256) void cvt_transpose(const float* __restrict__ in,
                                                     u16* __restrict__ out,
                                                     int R, int C) {
  __shared__ u16 tile[64 * 66];
  const int r0 = blockIdx.x * 64, c0 = blockIdx.y * 64;
  const int tid = threadIdx.x;
#pragma unroll
  for (int i = 0; i < 16; ++i) {
    int idx = i * 256 + tid;
    int r = idx >> 6, c = idx & 63;
    tile[r * 66 + c] = f2b(in[(size_t)(r0 + r) * C + (c0 + c)]);
  }
  __syncthreads();
#pragma unroll
  for (int i = 0; i < 16; ++i) {
    int idx = i * 256 + tid;
    int c = idx >> 6, r = idx & 63;
    out[(size_t)(c0 + c) * R + (r0 + r)] = tile[r * 66 + c];
  }
}

// ---------------- 128x128 GEMM core: C[m][n] = sum_k A[m][k]*Bt[n][k], K=1024 ----------------
__device__ __forceinline__ void gemm_tile_acc(const u16* __restrict__ A,
                                              const u16* __restrict__ Bt,
                                              int m0, int n0,
                                              u16* Alds, u16* Blds,
                                              f32x4 acc[4][4]) {
  const int tid = threadIdx.x;
  const int w = tid >> 6, lane = tid & 63;
  const int wm = w & 1, wn = w >> 1;
  const int col = lane & 15, quad = lane >> 4;
  const int lrow = lane >> 2;          // 0..15 within a 16-row group
  const int kseg = (lane & 3) * 8;     // 0,8,16,24
#pragma unroll
  for (int mt = 0; mt < 4; ++mt)
#pragma unroll
    for (int nt = 0; nt < 4; ++nt)
      acc[mt][nt] = (f32x4){0.f, 0.f, 0.f, 0.f};

  for (int k0 = 0; k0 < 1024; k0 += 32) {
    __syncthreads();   // previous compute done before LDS overwrite
#pragma unroll
    for (int g = 0; g < 2; ++g) {
      int grp = w * 2 + g;             // 0..7, each = 16 rows of the tile
      gld_lds16(A + (size_t)(m0 + grp * 16 + lrow) * 1024 + k0 + kseg,
                (char*)Alds + grp * 1024);
      gld_lds16(Bt + (size_t)(n0 + grp * 16 + lrow) * 1024 + k0 + kseg,
                (char*)Blds + grp * 1024);
    }
    __syncthreads();   // barrier drains vmcnt(0): staged data visible
    bf16x8 af[4], bfr[4];
#pragma unroll
    for (int mt = 0; mt < 4; ++mt)
      af[mt] = *(const bf16x8*)(Alds + (wm * 64 + mt * 16 + col) * 32 + quad * 8);
#pragma unroll
    for (int nt = 0; nt < 4; ++nt)
      bfr[nt] = *(const bf16x8*)(Blds + (wn * 64 + nt * 16 + col) * 32 + quad * 8);
#pragma unroll
    for (int mt = 0; mt < 4; ++mt)
#pragma unroll
      for (int nt = 0; nt < 4; ++nt)
        acc[mt][nt] = __builtin_amdgcn_mfma_f32_16x16x32_bf16(af[mt], bfr[nt],
                                                              acc[mt][nt], 0, 0, 0);
  }
}

// GEMM1: Xb @ WqkvT^T + b -> Q (pre-scaled), K (B,H,T,D) and V^T (B,H,D,T)
__global__ __launch_bounds__(256) void gemm_qkv(const u16* __restrict__ X,
                                                const u16* __restrict__ WT,
                                                const float* __restrict__ bias,
                                                u16* __restrict__ Q,
                                                u16* __restrict__ Kc,
                                                u16* __restrict__ Vt) {
  __shared__ __align__(16) u16 Alds[128 * 32];
  __shared__ __align__(16) u16 Blds[128 * 32];
  f32x4 acc[4][4];
  const int m0 = blockIdx.x * 128, n0 = blockIdx.y * 128;
  gemm_tile_acc(X, WT, m0, n0, Alds, Blds, acc);

  const float qscale = 0.18033688011112042f;   // 1/sqrt(D) * log2(e)
  const int tid = threadIdx.x;
  const int w = tid >> 6, lane = tid & 63;
  const int wm = w & 1, wn = w >> 1;
  const int col = lane & 15, quad = lane >> 4;
#pragma unroll
  for (int mt = 0; mt < 4; ++mt)
#pragma unroll
    for (int nt = 0; nt < 4; ++nt) {
      int n = n0 + wn * 64 + nt * 16 + col;
      int s = n >> 10, hh = (n >> 6) & (Hn - 1), d = n & 63;
      int mBase = m0 + wm * 64 + mt * 16 + quad * 4;
      int b = mBase >> 11, t0 = mBase & (Tsz - 1);
      if (s == 2) {
        // V^T: (b,h,d,t) — 4 consecutive t, one 8B store
        u32x2 pv;
        pv.x = pk2(acc[mt][nt][0] + bias[n], acc[mt][nt][1] + bias[n]);
        pv.y = pk2(acc[mt][nt][2] + bias[n], acc[mt][nt][3] + bias[n]);
        *(u32x2*)(Vt + ((size_t)(b * Hn + hh) * Dh + d) * Tsz + t0) = pv;
      } else {
        const float scl = (s == 0) ? qscale : 1.f;
        u16* dst = (s == 0) ? Q : Kc;
#pragma unroll
        for (int r = 0; r < 4; ++r)
          dst[((size_t)(b * Hn + hh) * Tsz + (t0 + r)) * Dh + d] =
              f2b((acc[mt][nt][r] + bias[n]) * scl);
      }
    }
}

// GEMM2: Ob(8192x1024) @ WprojT(1024x1024)^T + b -> fp32 out (B,T,C)
__global__ __launch_bounds__(256) void gemm_proj(const u16* __restrict__ O,
                                                 const u16* __restrict__ WT,
                                                 const float* __restrict__ bias,
                                                 float* __restrict__ out) {
  __shared__ __align__(16) u16 Alds[128 * 32];
  __shared__ __align__(16) u16 Blds[128 * 32];
  f32x4 acc[4][4];
  const int m0 = blockIdx.x * 128, n0 = blockIdx.y * 128;
  gemm_tile_acc(O, WT, m0, n0, Alds, Blds, acc);

  const int tid = threadIdx.x;
  const int w = tid >> 6, lane = tid & 63;
  const int wm = w & 1, wn = w >> 1;
  const int col = lane & 15, quad = lane >> 4;
#pragma unroll
  for (int mt = 0; mt < 4; ++mt)
#pragma unroll
    for (int nt = 0; nt < 4; ++nt)
#pragma unroll
      for (int r = 0; r < 4; ++r) {
        int m = m0 + wm * 64 + mt * 16 + quad * 4 + r;
        int n = n0 + wn * 64 + nt * 16 + col;
        out[(size_t)m * Csz + n] = acc[mt][nt][r] + bias[n];
      }
}

// ---------------- flash attention, round 7 ----------------
// 64 q-rows/block, 4 waves x 16 rows. Fixed-max softmax (Q pre-scaled by
// 1/sqrt(D)*log2e upstream). 64-key stages, async gld_lds double buffer,
// one barrier per stage. K [64 key][64 d], V^T [64 d][64 key], both 128B rows
// XOR-swizzled seg^(row&7). P kept in registers:
//   sacc[kt] = mfma(Kfrag, Qfrag)  -> S^T[key=kt*16+quad*4+r][q=col]
//   cvt_pk->bf16, permlane32_swap + permlane16_swap -> PV B-frag
//   oacc[dt] = mfma(V^Tfrag, Pfrag) -> O^T[d=dt*16+quad*4+r][q=col]
__global__ __launch_bounds__(256, 5) void attn(const u16* __restrict__ Q,
                                               const u16* __restrict__ Kg,
                                               const u16* __restrict__ Vt,
                                               u16* __restrict__ O) {
  __shared__ __align__(16) u16 Ks[2][64 * 64];      // [buf][key][d]  (DMA, swizzled segs)
  __shared__ __align__(16) u16 Vs[2][64 * 64];      // [buf][d][key]  (DMA, swizzled segs)

  // XCD-clustering bijective swizzle: dispatch id d -> xcd d%8. All 32
  // q-blocks of one (b,h) on one XCD so K/V stays in that XCD's L2.
  const int d0 = blockIdx.x + (blockIdx.y << 5) + (blockIdx.z << 9);
  const int xcd = d0 & 7, rest = d0 >> 3;
  const int j = rest & 31, ghi = rest >> 5;
  const int bh = (ghi << 3) + xcd;                  // 0..63 == b*Hn + h
  const int qt = 31 - j;                            // LPT within XCD
  const int h = bh & (Hn - 1), b = bh >> 4;

  const int tid = threadIdx.x, w = tid >> 6, lane = tid & 63;
  const int col = lane & 15, quad = lane >> 4;
  const int qbase = qt * 64;

  const u16* Kbase = Kg + (size_t)bh * Tsz * Dh;    // (key, d) rows of 64
  const u16* Vbase = Vt + (size_t)bh * Dh * Tsz;    // (d, key) rows of 2048

  // Q fragments straight from global (one-time; compiler inserts vmcnt wait)
  const u16* Qg = Q + ((size_t)bh * Tsz + qbase) * Dh;
  bf16x8 aq[2];
#pragma unroll
  for (int ks = 0; ks < 2; ++ks)
    aq[ks] = *(const bf16x8*)(Qg + (size_t)(w * 16 + col) * Dh + ks * 32 + quad * 8);

  // staging coords: LDS byte = g*4096 + tid*16 -> row = g*32 + (tid>>3),
  // physseg = tid&7; source pre-swizzled: seg = physseg ^ (row&7).
  const int xseg = ((tid & 7) ^ ((tid >> 3) & 7)) * 8;  // u16 units
  const size_t koff = (size_t)(tid >> 3) * 64 + xseg;    // within K stage tile
  const size_t voff = (size_t)(tid >> 3) * Tsz + xseg;   // within V rows
  const int swz = col & 7;                               // read-side XOR
  // read-side swizzled segment offsets (u16 units), loop-invariant
  const int off0 = ((0 + quad) ^ swz) << 3;              // ks/ksg = 0
  const int off1 = ((4 + quad) ^ swz) << 3;              // ks/ksg = 1

  f32x4 oacc[4];
#pragma unroll
  for (int dt = 0; dt < 4; ++dt) oacc[dt] = (f32x4){0.f, 0.f, 0.f, 0.f};
  float lsum[4] = {0.f, 0.f, 0.f, 0.f};   // independent per-kt partials

  const int nst = qt + 1;           // 64-key stages
  // preload stage 0 (2 calls each: rows 0-31, 32-63)
  gld_lds16(Kbase + koff, &Ks[0][w * 512]);
  gld_lds16(Kbase + 2048 + koff, &Ks[0][2048 + w * 512]);
  gld_lds16(Vbase + voff, &Vs[0][w * 512]);
  gld_lds16(Vbase + (size_t)32 * Tsz + voff, &Vs[0][2048 + w * 512]);

  // incremented DMA source pointers (stage s+1)
  const u16* kdma = Kbase + 4096 + koff;
  const u16* vdma = Vbase + 64 + voff;

  for (int s = 0; s < nst; ++s) {
    __syncthreads();   // drains DMA for buf[s&1]; all reads of buf (s-1) done
    const int cur = s & 1;
    if (s + 1 < nst) {
      const int nxt = cur ^ 1;
      gld_lds16(kdma, &Ks[nxt][w * 512]);
      gld_lds16(kdma + 2048, &Ks[nxt][2048 + w * 512]);
      gld_lds16(vdma, &Vs[nxt][w * 512]);
      gld_lds16(vdma + (size_t)32 * Tsz, &Vs[nxt][2048 + w * 512]);
      kdma += 4096;
      vdma += 64;
    }

    // S^T = K Q^T  (4 key-tiles of 16, contraction d=64 = 2 ks)
    f32x4 sacc[4];
#pragma unroll
    for (int kt = 0; kt < 4; ++kt) sacc[kt] = (f32x4){0.f, 0.f, 0.f, 0.f};
    __builtin_amdgcn_s_setprio(1);
#pragma unroll
    for (int ks = 0; ks < 2; ++ks)
#pragma unroll
      for (int kt = 0; kt < 4; ++kt) {
        bf16x8 bk = *(const bf16x8*)(
            &Ks[cur][(kt * 16 + col) * 64 + (ks ? off1 : off0)]);
        sacc[kt] = __builtin_amdgcn_mfma_f32_16x16x32_bf16(bk, aq[ks],
                                                           sacc[kt], 0, 0, 0);
      }
    __builtin_amdgcn_s_setprio(0);

    // P^T = exp2(S^T) in registers; mask only the diagonal stage (s == qt)
    float e[4][4];
    if (s == qt) {
      const int qg = w * 16 + col;            // q local == global - qbase
#pragma unroll
      for (int kt = 0; kt < 4; ++kt)
#pragma unroll
        for (int r = 0; r < 4; ++r) {
          int kl = kt * 16 + quad * 4 + r;    // key local == global - qbase
          float p = (kl > qg) ? 0.f : exp2f(sacc[kt][r]);
          lsum[kt] += p;
          e[kt][r] = p;
        }
    } else {
#pragma unroll
      for (int kt = 0; kt < 4; ++kt)
#pragma unroll
        for (int r = 0; r < 4; ++r) {
          float p = exp2f(sacc[kt][r]);
          lsum[kt] += p;
          e[kt][r] = p;
        }
    }

    // per 32-key half: build PV B-frag via permlane exchange, accumulate O^T
#pragma unroll
    for (int ksg = 0; ksg < 2; ++ksg) {
      // lane (col,quad) holds keys 32*ksg + {4q..4q+3} (lo kt) and +16 (hi kt)
      unsigned w00 = pk2(e[2 * ksg][0], e[2 * ksg][1]);
      unsigned w01 = pk2(e[2 * ksg][2], e[2 * ksg][3]);
      unsigned w10 = pk2(e[2 * ksg + 1][0], e[2 * ksg + 1][1]);
      unsigned w11 = pk2(e[2 * ksg + 1][2], e[2 * ksg + 1][3]);
      // 32-swap then 16-swap: word0 = keys {8q,8q+1}, word2 = {8q+4,8q+5}
      auto ra = __builtin_amdgcn_permlane32_swap(w00, w10, false, false);
      auto rb = __builtin_amdgcn_permlane32_swap(w01, w11, false, false);
      auto sa = __builtin_amdgcn_permlane16_swap(ra[0], ra[1], false, false);
      auto sb = __builtin_amdgcn_permlane16_swap(rb[0], rb[1], false, false);
      union { unsigned u[4]; bf16x8 v; } pf;
      pf.u[0] = sa[0]; pf.u[1] = sb[0]; pf.u[2] = sa[1]; pf.u[3] = sb[1];
      __builtin_amdgcn_s_setprio(1);
#pragma unroll
      for (int dt = 0; dt < 4; ++dt) {
        bf16x8 bv = *(const bf16x8*)(
            &Vs[cur][(dt * 16 + col) * 64 + (ksg ? off1 : off0)]);
        oacc[dt] = __builtin_amdgcn_mfma_f32_16x16x32_bf16(bv, pf.v,
                                                           oacc[dt], 0, 0, 0);
      }
      __builtin_amdgcn_s_setprio(0);
    }
  }

  // l reduction: merge partials, then keys spread across quads -> xor 16, 32
  float v = (lsum[0] + lsum[1]) + (lsum[2] + lsum[3]);
  v += __shfl_xor(v, 16);
  v += __shfl_xor(v, 32);
  const float inv = 1.0f / v;

  // epilogue: O[b, t=qbase+w*16+col, h, d=dt*16+quad*4+r] = oacc^T / l
  const int rg = qbase + w * 16 + col;
  u16* Orow = O + (((size_t)b * Tsz + rg) * Hn + h) * Dh;
#pragma unroll
  for (int dt = 0; dt < 4; ++dt) {
    u32x2 pv;
    pv.x = pk2(oacc[dt][0] * inv, oacc[dt][1] * inv);
    pv.y = pk2(oacc[dt][2] * inv, oacc[dt][3] * inv);
    *(u32x2*)(Orow + dt * 16 + quad * 4) = pv;
  }
}

extern "C" void kernel_launch(void* const* d_in, const int* in_sizes, int n_in,
                              void* d_out, int out_size, void* d_ws, size_t ws_size,
                              hipStream_t stream) {
  const float* x      = (const float*)d_in[0];
  const float* w_qkv  = (const float*)d_in[1];
  const float* b_qkv  = (const float*)d_in[2];
  const float* w_proj = (const float*)d_in[3];
  const float* b_proj = (const float*)d_in[4];
  float* out = (float*)d_out;

  // workspace layout (u16 elements), total 72 MB
  u16* Xb     = (u16*)d_ws;                          // 8192*1024
  u16* WqkvT  = Xb + (size_t)8192 * 1024;            // 3072*1024
  u16* WprojT = WqkvT + (size_t)3072 * 1024;         // 1024*1024
  u16* Qb     = WprojT + (size_t)1024 * 1024;        // 8192*1024 (pre-scaled)
  u16* Kb     = Qb + (size_t)8192 * 1024;            // 8192*1024
  u16* Ob     = Kb + (size_t)8192 * 1024;            // 8192*1024 (B,T,H,D)
  // d_out doubles as scratch: V^T (B,H,D,T) bf16, 16 MB; overwritten by gemm_proj
  u16* Vtb    = (u16*)d_out;                         // 8192*1024

  cvt_f32_bf16<<<4096, 256, 0, stream>>>(x, Xb);
  cvt_transpose<<<dim3(16, 48), 256, 0, stream>>>(w_qkv, WqkvT, 1024, 3072);
  cvt_transpose<<<dim3(16, 16), 256, 0, stream>>>(w_proj, WprojT, 1024, 1024);
  gemm_qkv<<<dim3(64, 24), 256, 0, stream>>>(Xb, WqkvT, b_qkv, Qb, Kb, Vtb);
  attn<<<dim3(32, 16, 4), 256, 0, stream>>>(Qb, Kb, Vtb, Ob);
  gemm_proj<<<dim3(64, 8), 256, 0, stream>>>(Ob, WprojT, b_proj, out);
}

// Round 4
// 273.561 us; speedup vs baseline: 1.1710x; 1.1710x over previous
//
#include <hip/hip_runtime.h>
#include <hip/hip_bf16.h>

// Causal MHA forward, B=4 T=2048 C=1024 H=16 D=64. fp32 in/out, bf16 MFMA inside.
// Round 8: revert round-7 regressions (inline-asm cvt_pk was -37% per m240;
// setprio hurts lockstep per m190) back to verified round-6 forms, and fix the
// real stall: per-stage __syncthreads drained vmcnt(0) including the fresh
// prefetch. Now: triple-buffered K/V stages, counted s_waitcnt vmcnt(4) + raw
// s_barrier (T3/T4). DMA for stage s+2 issued in iter s -> two stage-times of
// latency cover; the wait only retires the oldest 4 ops (own stage-s DMA).
// Kept from rounds 5-7: in-register P (swapped QK^T + permlane), XOR-swizzled
// 64-key K/V tiles (conflict-free), XCD clustering, lsum partials.

#define Bsz 4
#define Tsz 2048
#define Csz 1024
#define Hn  16
#define Dh  64

typedef unsigned short u16;
typedef __attribute__((ext_vector_type(8))) short bf16x8;   // 8 bf16 = 4 VGPRs
typedef __attribute__((ext_vector_type(4))) float f32x4;
typedef __attribute__((ext_vector_type(4))) unsigned int u32x4;
typedef __attribute__((ext_vector_type(2))) unsigned int u32x2;

__device__ __forceinline__ u16 f2b(float f) {
  __hip_bfloat16 h = __float2bfloat16(f);
  return *reinterpret_cast<u16*>(&h);
}

// two floats -> packed bf16 pair (lo in bits 15:0); compiler lowers well (m240)
__device__ __forceinline__ unsigned pk2(float lo, float hi) {
  return (unsigned)f2b(lo) | ((unsigned)f2b(hi) << 16);
}

// async global->LDS, 16B per lane; lds base must be wave-uniform (lane*16 implicit)
__device__ __forceinline__ void gld_lds16(const void* g, void* lds) {
  __builtin_amdgcn_global_load_lds(
      (const __attribute__((address_space(1))) unsigned int*)g,
      (__attribute__((address_space(3))) unsigned int*)lds, 16, 0, 0);
}

// ---------------- fp32 -> bf16 elementwise (8 elems/thread) ----------------
__global__ __launch_bounds__(256) void cvt_f32_bf16(const float* __restrict__ in,
                                                    u16* __restrict__ out) {
  size_t i = ((size_t)blockIdx.x * 256 + threadIdx.x) * 8;
  f32x4 a = *(const f32x4*)(in + i);
  f32x4 b = *(const f32x4*)(in + i + 4);
  u16 r[8];
#pragma unroll
  for (int j = 0; j < 4; ++j) { r[j] = f2b(a[j]); r[4 + j] = f2b(b[j]); }
  *(u32x4*)(out + i) = *(const u32x4*)r;
}

// ---------------- fp32 (R,C) -> bf16 transposed (C,R) ----------------
__global__ __launch_bounds__(256) void cvt_transpose(const float* __restrict__ in,
                                                     u16* __restrict__ out,
                                                     int R, int C) {
  __shared__ u16 tile[64 * 66];
  const int r0 = blockIdx.x * 64, c0 = blockIdx.y * 64;
  const int tid = threadIdx.x;
#pragma unroll
  for (int i = 0; i < 16; ++i) {
    int idx = i * 256 + tid;
    int r = idx >> 6, c = idx & 63;
    tile[r * 66 + c] = f2b(in[(size_t)(r0 + r) * C + (c0 + c)]);
  }
  __syncthreads();
#pragma unroll
  for (int i = 0; i < 16; ++i) {
    int idx = i * 256 + tid;
    int c = idx >> 6, r = idx & 63;
    out[(size_t)(c0 + c) * R + (r0 + r)] = tile[r * 66 + c];
  }
}

// ---------------- 128x128 GEMM core: C[m][n] = sum_k A[m][k]*Bt[n][k], K=1024 ----------------
__device__ __forceinline__ void gemm_tile_acc(const u16* __restrict__ A,
                                              const u16* __restrict__ Bt,
                                              int m0, int n0,
                                              u16* Alds, u16* Blds,
                                              f32x4 acc[4][4]) {
  const int tid = threadIdx.x;
  const int w = tid >> 6, lane = tid & 63;
  const int wm = w & 1, wn = w >> 1;
  const int col = lane & 15, quad = lane >> 4;
  const int lrow = lane >> 2;          // 0..15 within a 16-row group
  const int kseg = (lane & 3) * 8;     // 0,8,16,24
#pragma unroll
  for (int mt = 0; mt < 4; ++mt)
#pragma unroll
    for (int nt = 0; nt < 4; ++nt)
      acc[mt][nt] = (f32x4){0.f, 0.f, 0.f, 0.f};

  for (int k0 = 0; k0 < 1024; k0 += 32) {
    __syncthreads();   // previous compute done before LDS overwrite
#pragma unroll
    for (int g = 0; g < 2; ++g) {
      int grp = w * 2 + g;             // 0..7, each = 16 rows of the tile
      gld_lds16(A + (size_t)(m0 + grp * 16 + lrow) * 1024 + k0 + kseg,
                (char*)Alds + grp * 1024);
      gld_lds16(Bt + (size_t)(n0 + grp * 16 + lrow) * 1024 + k0 + kseg,
                (char*)Blds + grp * 1024);
    }
    __syncthreads();   // barrier drains vmcnt(0): staged data visible
    bf16x8 af[4], bfr[4];
#pragma unroll
    for (int mt = 0; mt < 4; ++mt)
      af[mt] = *(const bf16x8*)(Alds + (wm * 64 + mt * 16 + col) * 32 + quad * 8);
#pragma unroll
    for (int nt = 0; nt < 4; ++nt)
      bfr[nt] = *(const bf16x8*)(Blds + (wn * 64 + nt * 16 + col) * 32 + quad * 8);
#pragma unroll
    for (int mt = 0; mt < 4; ++mt)
#pragma unroll
      for (int nt = 0; nt < 4; ++nt)
        acc[mt][nt] = __builtin_amdgcn_mfma_f32_16x16x32_bf16(af[mt], bfr[nt],
                                                              acc[mt][nt], 0, 0, 0);
  }
}

// GEMM1: Xb @ WqkvT^T + b -> Q (pre-scaled), K (B,H,T,D) and V^T (B,H,D,T)
__global__ __launch_bounds__(256) void gemm_qkv(const u16* __restrict__ X,
                                                const u16* __restrict__ WT,
                                                const float* __restrict__ bias,
                                                u16* __restrict__ Q,
                                                u16* __restrict__ Kc,
                                                u16* __restrict__ Vt) {
  __shared__ __align__(16) u16 Alds[128 * 32];
  __shared__ __align__(16) u16 Blds[128 * 32];
  f32x4 acc[4][4];
  const int m0 = blockIdx.x * 128, n0 = blockIdx.y * 128;
  gemm_tile_acc(X, WT, m0, n0, Alds, Blds, acc);

  const float qscale = 0.18033688011112042f;   // 1/sqrt(D) * log2(e)
  const int tid = threadIdx.x;
  const int w = tid >> 6, lane = tid & 63;
  const int wm = w & 1, wn = w >> 1;
  const int col = lane & 15, quad = lane >> 4;
#pragma unroll
  for (int mt = 0; mt < 4; ++mt)
#pragma unroll
    for (int nt = 0; nt < 4; ++nt) {
      int n = n0 + wn * 64 + nt * 16 + col;
      int s = n >> 10, hh = (n >> 6) & (Hn - 1), d = n & 63;
      int mBase = m0 + wm * 64 + mt * 16 + quad * 4;
      int b = mBase >> 11, t0 = mBase & (Tsz - 1);
      if (s == 2) {
        // V^T: (b,h,d,t) — 4 consecutive t, one 8B store
        u16 vals[4];
#pragma unroll
        for (int r = 0; r < 4; ++r) vals[r] = f2b(acc[mt][nt][r] + bias[n]);
        *(u32x2*)(Vt + ((size_t)(b * Hn + hh) * Dh + d) * Tsz + t0) =
            *(const u32x2*)vals;
      } else {
        const float scl = (s == 0) ? qscale : 1.f;
        u16* dst = (s == 0) ? Q : Kc;
#pragma unroll
        for (int r = 0; r < 4; ++r)
          dst[((size_t)(b * Hn + hh) * Tsz + (t0 + r)) * Dh + d] =
              f2b((acc[mt][nt][r] + bias[n]) * scl);
      }
    }
}

// GEMM2: Ob(8192x1024) @ WprojT(1024x1024)^T + b -> fp32 out (B,T,C)
__global__ __launch_bounds__(256) void gemm_proj(const u16* __restrict__ O,
                                                 const u16* __restrict__ WT,
                                                 const float* __restrict__ bias,
                                                 float* __restrict__ out) {
  __shared__ __align__(16) u16 Alds[128 * 32];
  __shared__ __align__(16) u16 Blds[128 * 32];
  f32x4 acc[4][4];
  const int m0 = blockIdx.x * 128, n0 = blockIdx.y * 128;
  gemm_tile_acc(O, WT, m0, n0, Alds, Blds, acc);

  const int tid = threadIdx.x;
  const int w = tid >> 6, lane = tid & 63;
  const int wm = w & 1, wn = w >> 1;
  const int col = lane & 15, quad = lane >> 4;
#pragma unroll
  for (int mt = 0; mt < 4; ++mt)
#pragma unroll
    for (int nt = 0; nt < 4; ++nt)
#pragma unroll
      for (int r = 0; r < 4; ++r) {
        int m = m0 + wm * 64 + mt * 16 + quad * 4 + r;
        int n = n0 + wn * 64 + nt * 16 + col;
        out[(size_t)m * Csz + n] = acc[mt][nt][r] + bias[n];
      }
}

// ---------------- flash attention, round 8 ----------------
// 64 q-rows/block, 4 waves x 16 rows. Fixed-max softmax (Q pre-scaled by
// 1/sqrt(D)*log2e upstream). 64-key stages, TRIPLE-buffered async gld_lds:
//   iter s: s_waitcnt vmcnt(4) (own stage-s DMA done, stage-s+1 still in
//   flight) -> s_barrier (all waves' stage-s done) -> issue DMA(s+2) ->
//   compute stage s. Prefetch gets ~2 stage-times to land; never drained.
// K [64 key][64 d], V^T [64 d][64 key], both 128B rows XOR-swizzled
// seg^(row&7) (pre-swizzled global src, linear DMA dest, swizzled read).
// P in registers: sacc = mfma(Kfrag, Qfrag) -> S^T; pack + permlane32/16_swap
// -> PV B-frag; oacc = mfma(V^Tfrag, Pfrag) -> O^T.
__global__ __launch_bounds__(256, 3) void attn(const u16* __restrict__ Q,
                                               const u16* __restrict__ Kg,
                                               const u16* __restrict__ Vt,
                                               u16* __restrict__ O) {
  __shared__ __align__(16) u16 Ks[3][64 * 64];      // [buf][key][d]  (DMA, swizzled segs)
  __shared__ __align__(16) u16 Vs[3][64 * 64];      // [buf][d][key]  (DMA, swizzled segs)

  // XCD-clustering bijective swizzle: dispatch id d -> xcd d%8. All 32
  // q-blocks of one (b,h) on one XCD so K/V stays in that XCD's L2.
  const int d0 = blockIdx.x + (blockIdx.y << 5) + (blockIdx.z << 9);
  const int xcd = d0 & 7, rest = d0 >> 3;
  const int j = rest & 31, ghi = rest >> 5;
  const int bh = (ghi << 3) + xcd;                  // 0..63 == b*Hn + h
  const int qt = 31 - j;                            // LPT within XCD
  const int h = bh & (Hn - 1), b = bh >> 4;

  const int tid = threadIdx.x, w = tid >> 6, lane = tid & 63;
  const int col = lane & 15, quad = lane >> 4;
  const int qbase = qt * 64;

  const u16* Kbase = Kg + (size_t)bh * Tsz * Dh;    // (key, d) rows of 64
  const u16* Vbase = Vt + (size_t)bh * Dh * Tsz;    // (d, key) rows of 2048

  // Q fragments straight from global (one-time)
  const u16* Qg = Q + ((size_t)bh * Tsz + qbase) * Dh;
  bf16x8 aq[2];
#pragma unroll
  for (int ks = 0; ks < 2; ++ks)
    aq[ks] = *(const bf16x8*)(Qg + (size_t)(w * 16 + col) * Dh + ks * 32 + quad * 8);
  // retire Q loads now so the compiler never inserts a vmcnt wait inside the
  // loop that would drain in-flight LDS prefetches
  asm volatile("s_waitcnt vmcnt(0)" ::: "memory");

  // staging coords: LDS byte = g*4096 + tid*16 -> row = g*32 + (tid>>3),
  // physseg = tid&7; source pre-swizzled: seg = physseg ^ (row&7).
  const int xseg = ((tid & 7) ^ ((tid >> 3) & 7)) * 8;  // u16 units
  const size_t koff = (size_t)(tid >> 3) * 64 + xseg;    // within K stage tile
  const size_t voff = (size_t)(tid >> 3) * Tsz + xseg;   // within V rows
  const int swz = col & 7;                               // read-side XOR
  // read-side swizzled segment offsets (u16 units), loop-invariant
  const int off0 = ((0 + quad) ^ swz) << 3;              // ks/ksg = 0
  const int off1 = ((4 + quad) ^ swz) << 3;              // ks/ksg = 1

  f32x4 oacc[4];
#pragma unroll
  for (int dt = 0; dt < 4; ++dt) oacc[dt] = (f32x4){0.f, 0.f, 0.f, 0.f};
  float lsum[4] = {0.f, 0.f, 0.f, 0.f};   // independent per-kt partials

  const int nst = qt + 1;           // 64-key stages
  // prologue: issue stages 0 and 1 (4 DMA ops each per wave)
  gld_lds16(Kbase + koff, &Ks[0][w * 512]);
  gld_lds16(Kbase + 2048 + koff, &Ks[0][2048 + w * 512]);
  gld_lds16(Vbase + voff, &Vs[0][w * 512]);
  gld_lds16(Vbase + (size_t)32 * Tsz + voff, &Vs[0][2048 + w * 512]);
  if (1 < nst) {
    gld_lds16(Kbase + 4096 + koff, &Ks[1][w * 512]);
    gld_lds16(Kbase + 4096 + 2048 + koff, &Ks[1][2048 + w * 512]);
    gld_lds16(Vbase + 64 + voff, &Vs[1][w * 512]);
    gld_lds16(Vbase + 64 + (size_t)32 * Tsz + voff, &Vs[1][2048 + w * 512]);
  }
  // DMA source pointers for stage s+2
  const u16* kdma = Kbase + 2 * 4096 + koff;
  const u16* vdma = Vbase + 2 * 64 + voff;

  int cur = 0;                       // LDS slot of stage s
  for (int s = 0; s < nst; ++s) {
    // own stage-s DMA (oldest 4 ops) retired; stage-s+1 stays in flight
    if (s + 1 < nst) {
      asm volatile("s_waitcnt vmcnt(4)" ::: "memory");
    } else {
      asm volatile("s_waitcnt vmcnt(0)" ::: "memory");
    }
    __builtin_amdgcn_s_barrier();    // all waves' stage-s quarters visible;
    __builtin_amdgcn_sched_barrier(0);
    // safe to overwrite slot (s+2)%3 == (s-1)%3: all waves past compute(s-1)
    if (s + 2 < nst) {
      int pf = cur + 2; if (pf >= 3) pf -= 3;
      gld_lds16(kdma, &Ks[pf][w * 512]);
      gld_lds16(kdma + 2048, &Ks[pf][2048 + w * 512]);
      gld_lds16(vdma, &Vs[pf][w * 512]);
      gld_lds16(vdma + (size_t)32 * Tsz, &Vs[pf][2048 + w * 512]);
      kdma += 4096;
      vdma += 64;
    }

    // S^T = K Q^T  (4 key-tiles of 16, contraction d=64 = 2 ks)
    f32x4 sacc[4];
#pragma unroll
    for (int kt = 0; kt < 4; ++kt) sacc[kt] = (f32x4){0.f, 0.f, 0.f, 0.f};
#pragma unroll
    for (int ks = 0; ks < 2; ++ks)
#pragma unroll
      for (int kt = 0; kt < 4; ++kt) {
        bf16x8 bk = *(const bf16x8*)(
            &Ks[cur][(kt * 16 + col) * 64 + (ks ? off1 : off0)]);
        sacc[kt] = __builtin_amdgcn_mfma_f32_16x16x32_bf16(bk, aq[ks],
                                                           sacc[kt], 0, 0, 0);
      }

    // P^T = exp2(S^T) in registers; mask only the diagonal stage (s == qt)
    float e[4][4];
    if (s == qt) {
      const int qg = w * 16 + col;            // q local == global - qbase
#pragma unroll
      for (int kt = 0; kt < 4; ++kt)
#pragma unroll
        for (int r = 0; r < 4; ++r) {
          int kl = kt * 16 + quad * 4 + r;    // key local == global - qbase
          float p = (kl > qg) ? 0.f : exp2f(sacc[kt][r]);
          lsum[kt] += p;
          e[kt][r] = p;
        }
    } else {
#pragma unroll
      for (int kt = 0; kt < 4; ++kt)
#pragma unroll
        for (int r = 0; r < 4; ++r) {
          float p = exp2f(sacc[kt][r]);
          lsum[kt] += p;
          e[kt][r] = p;
        }
    }

    // per 32-key half: build PV B-frag via permlane exchange, accumulate O^T
#pragma unroll
    for (int ksg = 0; ksg < 2; ++ksg) {
      // lane (col,quad) holds keys 32*ksg + {4q..4q+3} (lo kt) and +16 (hi kt)
      unsigned w00 = pk2(e[2 * ksg][0], e[2 * ksg][1]);
      unsigned w01 = pk2(e[2 * ksg][2], e[2 * ksg][3]);
      unsigned w10 = pk2(e[2 * ksg + 1][0], e[2 * ksg + 1][1]);
      unsigned w11 = pk2(e[2 * ksg + 1][2], e[2 * ksg + 1][3]);
      // 32-swap then 16-swap: word0 = keys {8q,8q+1}, word2 = {8q+4,8q+5}
      auto ra = __builtin_amdgcn_permlane32_swap(w00, w10, false, false);
      auto rb = __builtin_amdgcn_permlane32_swap(w01, w11, false, false);
      auto sa = __builtin_amdgcn_permlane16_swap(ra[0], ra[1], false, false);
      auto sb = __builtin_amdgcn_permlane16_swap(rb[0], rb[1], false, false);
      union { unsigned u[4]; bf16x8 v; } pf;
      pf.u[0] = sa[0]; pf.u[1] = sb[0]; pf.u[2] = sa[1]; pf.u[3] = sb[1];
#pragma unroll
      for (int dt = 0; dt < 4; ++dt) {
        bf16x8 bv = *(const bf16x8*)(
            &Vs[cur][(dt * 16 + col) * 64 + (ksg ? off1 : off0)]);
        oacc[dt] = __builtin_amdgcn_mfma_f32_16x16x32_bf16(bv, pf.v,
                                                           oacc[dt], 0, 0, 0);
      }
    }

    cur += 1; if (cur >= 3) cur = 0;
  }

  // l reduction: merge partials, then keys spread across quads -> xor 16, 32
  float v = (lsum[0] + lsum[1]) + (lsum[2] + lsum[3]);
  v += __shfl_xor(v, 16);
  v += __shfl_xor(v, 32);
  const float inv = 1.0f / v;

  // epilogue: O[b, t=qbase+w*16+col, h, d=dt*16+quad*4+r] = oacc^T / l
  const int rg = qbase + w * 16 + col;
  u16* Orow = O + (((size_t)b * Tsz + rg) * Hn + h) * Dh;
#pragma unroll
  for (int dt = 0; dt < 4; ++dt) {
    u16 vals[4];
#pragma unroll
    for (int r = 0; r < 4; ++r) vals[r] = f2b(oacc[dt][r] * inv);
    *(u32x2*)(Orow + dt * 16 + quad * 4) = *(const u32x2*)vals;
  }
}

extern "C" void kernel_launch(void* const* d_in, const int* in_sizes, int n_in,
                              void* d_out, int out_size, void* d_ws, size_t ws_size,
                              hipStream_t stream) {
  const float* x      = (const float*)d_in[0];
  const float* w_qkv  = (const float*)d_in[1];
  const float* b_qkv  = (const float*)d_in[2];
  const float* w_proj = (const float*)d_in[3];
  const float* b_proj = (const float*)d_in[4];
  float* out = (float*)d_out;

  // workspace layout (u16 elements), total 72 MB
  u16* Xb     = (u16*)d_ws;                          // 8192*1024
  u16* WqkvT  = Xb + (size_t)8192 * 1024;            // 3072*1024
  u16* WprojT = WqkvT + (size_t)3072 * 1024;         // 1024*1024
  u16* Qb     = WprojT + (size_t)1024 * 1024;        // 8192*1024 (pre-scaled)
  u16* Kb     = Qb + (size_t)8192 * 1024;            // 8192*1024
  u16* Ob     = Kb + (size_t)8192 * 1024;            // 8192*1024 (B,T,H,D)
  // d_out doubles as scratch: V^T (B,H,D,T) bf16, 16 MB; overwritten by gemm_proj
  u16* Vtb    = (u16*)d_out;                         // 8192*1024

  cvt_f32_bf16<<<4096, 256, 0, stream>>>(x, Xb);
  cvt_transpose<<<dim3(16, 48), 256, 0, stream>>>(w_qkv, WqkvT, 1024, 3072);
  cvt_transpose<<<dim3(16, 16), 256, 0, stream>>>(w_proj, WprojT, 1024, 1024);
  gemm_qkv<<<dim3(64, 24), 256, 0, stream>>>(Xb, WqkvT, b_qkv, Qb, Kb, Vtb);
  attn<<<dim3(32, 16, 4), 256, 0, stream>>>(Qb, Kb, Vtb, Ob);
  gemm_proj<<<dim3(64, 8), 256, 0, stream>>>(Ob, WprojT, b_proj, out);
}